// Round 1
// 837.517 us; speedup vs baseline: 1.0879x; 1.0879x over previous
//
#include <hip/hip_runtime.h>
#include <stdint.h>

typedef unsigned short u16;
typedef short bf16x8 __attribute__((ext_vector_type(8)));
typedef float f32x4 __attribute__((ext_vector_type(4)));

// B=2, S=2048, D=1024, H=16, DK=64. Inputs fp32, outputs fp32, mask int32.
static __device__ __forceinline__ u16 f2b(float f) {
    uint32_t u = __float_as_uint(f);
    uint32_t r = (u + 0x7fffu + ((u >> 16) & 1u)) >> 16;
    return (u16)r;
}
static __device__ __forceinline__ float b2f(u16 u) {
    union { float f; uint32_t i; } x; x.i = ((uint32_t)u) << 16; return x.f;
}

// async global->LDS, 16B per lane. LDS dest must be wave-uniform base + lane*16.
#define GLOAD16(g, l)                                                        \
    __builtin_amdgcn_global_load_lds(                                        \
        (const __attribute__((address_space(1))) uint32_t*)(g),              \
        (__attribute__((address_space(3))) uint32_t*)(l), 16, 0, 0)

// ---------- mask bit-pack: [B*S][2048] int32 -> [B*S][32] uint64 (bit set = masked) ----------
__global__ __launch_bounds__(256) void pack_mask_k(const int* __restrict__ mask,
                                                   unsigned long long* __restrict__ bits) {
    const int row = blockIdx.x;  // b*2048 + q
    const int wave = threadIdx.x >> 6, lane = threadIdx.x & 63;
    const int* mrow = mask + (size_t)row * 2048;
#pragma unroll
    for (int it = 0; it < 8; ++it) {
        int col = it * 256 + threadIdx.x;
        unsigned long long b = __ballot(mrow[col] != 0);
        if (lane == 0) bits[(size_t)row * 32 + it * 4 + wave] = b;
    }
}

// ---------- transpose + fp32->bf16 four 1024x1024 weights into [n][k] bf16 layout ----------
__global__ __launch_bounds__(256) void transpose_w_k(const float* __restrict__ Wq, const float* __restrict__ Wk,
                                                     const float* __restrict__ Wv, const float* __restrict__ Wo,
                                                     u16* __restrict__ WtAll) {
    __shared__ u16 t[32][36];
    const float* W = blockIdx.z == 0 ? Wq : blockIdx.z == 1 ? Wk : blockIdx.z == 2 ? Wv : Wo;
    u16* out = WtAll + (size_t)blockIdx.z * (1024u * 1024u);
    const int r = threadIdx.x >> 3, c4 = (threadIdx.x & 7) * 4;
    float4 v = *(const float4*)(W + (size_t)(blockIdx.y * 32 + r) * 1024 + blockIdx.x * 32 + c4);
    t[r][c4 + 0] = f2b(v.x); t[r][c4 + 1] = f2b(v.y); t[r][c4 + 2] = f2b(v.z); t[r][c4 + 3] = f2b(v.w);
    __syncthreads();
    ushort4 o;
    o.x = t[c4 + 0][r]; o.y = t[c4 + 1][r]; o.z = t[c4 + 2][r]; o.w = t[c4 + 3][r];
    *(ushort4*)(out + (size_t)(blockIdx.x * 32 + r) * 1024 + blockIdx.y * 32 + c4) = o;
}

// ---------- Q fp32 -> bf16 (same f2b rounding as the old in-GEMM conversion) ----------
__global__ __launch_bounds__(256) void qcvt_k(const float* __restrict__ Q, u16* __restrict__ qbf) {
    const size_t i = ((size_t)blockIdx.x * 256 + threadIdx.x) * 8;
    float4 a = *(const float4*)(Q + i);
    float4 b = *(const float4*)(Q + i + 4);
    bf16x8 o;
    o[0] = (short)f2b(a.x); o[1] = (short)f2b(a.y); o[2] = (short)f2b(a.z); o[3] = (short)f2b(a.w);
    o[4] = (short)f2b(b.x); o[5] = (short)f2b(b.y); o[6] = (short)f2b(b.z); o[7] = (short)f2b(b.w);
    *(bf16x8*)(qbf + i) = o;
}

// ---------- fused QKV projection: one GEMM M=4096 N=3072 K=1024, m97 structure ----------
// A = qbf [4096][1024] bf16, B = WtAll [3072][1024] bf16 (n-major, k contiguous).
// 128x128 tile, BK=32, 4 waves (2x2), global_load_lds width 16.
__global__ __launch_bounds__(256) void gemm_qkv_k(const u16* __restrict__ Abf, const u16* __restrict__ WtAll,
                                                  const float* __restrict__ bq, const float* __restrict__ bk,
                                                  const float* __restrict__ bv,
                                                  u16* __restrict__ q_ws, u16* __restrict__ k_ws,
                                                  u16* __restrict__ v_ws) {
    __shared__ u16 Asm[128 * 32];
    __shared__ u16 Bsm[128 * 32];
    const int tid = threadIdx.x;
    const int wave = tid >> 6, lane = tid & 63, quad = lane >> 4, l16 = lane & 15;
    const int wr = wave >> 1, wc = wave & 1;
    const int m0 = blockIdx.y * 128, n0 = blockIdx.x * 128;

    const u16* Ag = Abf + (size_t)(m0 + (tid >> 2)) * 1024 + (tid & 3) * 8;
    const u16* Bg = WtAll + (size_t)(n0 + (tid >> 2)) * 1024 + (tid & 3) * 8;

    const f32x4 zero = {0.f, 0.f, 0.f, 0.f};
    f32x4 acc[4][4];
#pragma unroll
    for (int i = 0; i < 4; ++i)
#pragma unroll
        for (int j = 0; j < 4; ++j) acc[i][j] = zero;

    for (int k0 = 0; k0 < 1024; k0 += 32) {
        GLOAD16(Ag + k0, &Asm[tid * 8]);
        GLOAD16(Ag + k0 + (size_t)64 * 1024, &Asm[2048 + tid * 8]);
        GLOAD16(Bg + k0, &Bsm[tid * 8]);
        GLOAD16(Bg + k0 + (size_t)64 * 1024, &Bsm[2048 + tid * 8]);
        __syncthreads();
        bf16x8 a[4], b[4];
#pragma unroll
        for (int i = 0; i < 4; ++i) {
            a[i] = *(const bf16x8*)&Asm[(wr * 64 + i * 16 + l16) * 32 + quad * 8];
            b[i] = *(const bf16x8*)&Bsm[(wc * 64 + i * 16 + l16) * 32 + quad * 8];
        }
#pragma unroll
        for (int mi = 0; mi < 4; ++mi)
#pragma unroll
            for (int ni = 0; ni < 4; ++ni)
                acc[mi][ni] = __builtin_amdgcn_mfma_f32_16x16x32_bf16(a[mi], b[ni], acc[mi][ni], 0, 0, 0);
        __syncthreads();
    }

    const int z = n0 >> 10;  // 128-col tiles never cross a 1024 boundary
    const float* bias = z == 0 ? bq : z == 1 ? bk : bv;
    u16* out = z == 0 ? q_ws : z == 1 ? k_ws : v_ws;
    const float oscale = (z == 0) ? 0.18033688011112042f : 1.0f;  // 0.125 * log2(e) for q
#pragma unroll
    for (int ni = 0; ni < 4; ++ni) {
        const int n = n0 + wc * 64 + ni * 16 + l16;
        const int nn = n & 1023, h = nn >> 6, d = nn & 63;
        const float bsf = bias[nn];
#pragma unroll
        for (int mi = 0; mi < 4; ++mi)
#pragma unroll
            for (int r = 0; r < 4; ++r) {
                const int m = m0 + wr * 64 + mi * 16 + quad * 4 + r;
                const int bb = m >> 11, s = m & 2047;
                out[((size_t)(bb * 16 + h) * 2048 + s) * 64 + d] = f2b((acc[mi][ni][r] + bsf) * oscale);
            }
    }
}

// ---------- V transpose: v_ws [bh][s][d] -> vT [bh][d][s] (for vectorized attn staging) ----------
__global__ __launch_bounds__(256) void vtr_k(const u16* __restrict__ v_ws, u16* __restrict__ vT) {
    __shared__ u16 t[32][36];
    const int bh = blockIdx.z, s0 = blockIdx.x * 32, d0 = blockIdx.y * 32;
    const int r = threadIdx.x >> 3, c4 = (threadIdx.x & 7) * 4;
    ushort4 v = *(const ushort4*)(v_ws + ((size_t)bh * 2048 + s0 + r) * 64 + d0 + c4);
    t[r][c4 + 0] = v.x; t[r][c4 + 1] = v.y; t[r][c4 + 2] = v.z; t[r][c4 + 3] = v.w;
    __syncthreads();
    ushort4 o;
    o.x = t[c4 + 0][r]; o.y = t[c4 + 1][r]; o.z = t[c4 + 2][r]; o.w = t[c4 + 3][r];
    *(ushort4*)(vT + ((size_t)bh * 64 + d0 + r) * 2048 + s0 + c4) = o;
}

// ---------- fused attention: scores -> softmax -> attn(fp32 out) + context(bf16) ----------
__global__ __launch_bounds__(256) void attn_k(const u16* __restrict__ q_ws, const u16* __restrict__ k_ws,
                                              const u16* __restrict__ vT,
                                              const unsigned long long* __restrict__ mbits,
                                              float* __restrict__ attn_out, u16* __restrict__ ctx_ws) {
    const int bh = blockIdx.y, b = bh >> 4, h = bh & 15;
    const int q0 = blockIdx.x * 64;
    const int tid = threadIdx.x;
    const int wave = tid >> 6, lane = tid & 63, quad = lane >> 4, l16 = lane & 15;

    __shared__ u16 Ksm[64][72];
    __shared__ u16 Vsm[64][72];
    __shared__ u16 Psm[4][16][72];

    const u16* qp = q_ws + ((size_t)bh * 2048 + q0 + wave * 16 + l16) * 64;
    const bf16x8 aq0 = *(const bf16x8*)(qp + quad * 8);
    const bf16x8 aq1 = *(const bf16x8*)(qp + 32 + quad * 8);

    const size_t mbase = ((size_t)b * 2048 + q0 + wave * 16 + quad * 4) * 32;

    const int r0 = tid >> 3, c0 = (tid & 7) * 8;
    const u16* kgb = k_ws + (size_t)bh * 2048 * 64;
    const u16* vtg = vT + (size_t)bh * 64 * 2048;

    const f32x4 zero = {0.f, 0.f, 0.f, 0.f};
    float lsum[4] = {0.f, 0.f, 0.f, 0.f};

    // phase 1: row sums of exp
    for (int kt = 0; kt < 32; ++kt) {
        const int s0 = kt * 64;
        *(bf16x8*)&Ksm[r0][c0] = *(const bf16x8*)(kgb + (size_t)(s0 + r0) * 64 + c0);
        *(bf16x8*)&Ksm[r0 + 32][c0] = *(const bf16x8*)(kgb + (size_t)(s0 + r0 + 32) * 64 + c0);
        __syncthreads();
        f32x4 sc[4];
#pragma unroll
        for (int nt = 0; nt < 4; ++nt) {
            sc[nt] = zero;
            bf16x8 bk0 = *(const bf16x8*)&Ksm[nt * 16 + l16][quad * 8];
            bf16x8 bk1 = *(const bf16x8*)&Ksm[nt * 16 + l16][32 + quad * 8];
            sc[nt] = __builtin_amdgcn_mfma_f32_16x16x32_bf16(aq0, bk0, sc[nt], 0, 0, 0);
            sc[nt] = __builtin_amdgcn_mfma_f32_16x16x32_bf16(aq1, bk1, sc[nt], 0, 0, 0);
        }
        unsigned long long mw[4];
#pragma unroll
        for (int r = 0; r < 4; ++r) mw[r] = mbits[mbase + (size_t)r * 32 + kt];
#pragma unroll
        for (int nt = 0; nt < 4; ++nt)
#pragma unroll
            for (int r = 0; r < 4; ++r) {
                const int bit = (int)((mw[r] >> (nt * 16 + l16)) & 1ull);
                lsum[r] += bit ? 0.f : exp2f(sc[nt][r]);
            }
        __syncthreads();
    }
#pragma unroll
    for (int r = 0; r < 4; ++r) {
#pragma unroll
        for (int off = 1; off < 16; off <<= 1) lsum[r] += __shfl_xor(lsum[r], off, 64);
    }
    float rl[4];
#pragma unroll
    for (int r = 0; r < 4; ++r) rl[r] = 1.0f / lsum[r];

    f32x4 cacc[4];
#pragma unroll
    for (int i = 0; i < 4; ++i) cacc[i] = zero;

    // phase 2: recompute scores, write normalized attn (fp32), accumulate context
    for (int kt = 0; kt < 32; ++kt) {
        const int s0 = kt * 64;
        *(bf16x8*)&Ksm[r0][c0] = *(const bf16x8*)(kgb + (size_t)(s0 + r0) * 64 + c0);
        *(bf16x8*)&Ksm[r0 + 32][c0] = *(const bf16x8*)(kgb + (size_t)(s0 + r0 + 32) * 64 + c0);
        // vectorized V staging from pre-transposed vT: Vsm[d][s_local]
        *(bf16x8*)&Vsm[r0][c0] = *(const bf16x8*)(vtg + (size_t)r0 * 2048 + s0 + c0);
        *(bf16x8*)&Vsm[r0 + 32][c0] = *(const bf16x8*)(vtg + (size_t)(r0 + 32) * 2048 + s0 + c0);
        __syncthreads();

        f32x4 sc[4];
#pragma unroll
        for (int nt = 0; nt < 4; ++nt) {
            sc[nt] = zero;
            bf16x8 bk0 = *(const bf16x8*)&Ksm[nt * 16 + l16][quad * 8];
            bf16x8 bk1 = *(const bf16x8*)&Ksm[nt * 16 + l16][32 + quad * 8];
            sc[nt] = __builtin_amdgcn_mfma_f32_16x16x32_bf16(aq0, bk0, sc[nt], 0, 0, 0);
            sc[nt] = __builtin_amdgcn_mfma_f32_16x16x32_bf16(aq1, bk1, sc[nt], 0, 0, 0);
        }
        unsigned long long mw[4];
#pragma unroll
        for (int r = 0; r < 4; ++r) mw[r] = mbits[mbase + (size_t)r * 32 + kt];
#pragma unroll
        for (int nt = 0; nt < 4; ++nt)
#pragma unroll
            for (int r = 0; r < 4; ++r) {
                const int bit = (int)((mw[r] >> (nt * 16 + l16)) & 1ull);
                const float p = bit ? 0.f : exp2f(sc[nt][r]) * rl[r];
                Psm[wave][quad * 4 + r][nt * 16 + l16] = f2b(p);
            }
        // coalesced fp32 attn store via per-wave LDS roundtrip (same-wave, no barrier needed)
#pragma unroll
        for (int j = 0; j < 4; ++j) {
            const int pr = j * 4 + (lane >> 4), pc = (lane & 15) * 4;
            ushort4 pv = *(const ushort4*)&Psm[wave][pr][pc];
            float4 pf;
            pf.x = b2f(pv.x); pf.y = b2f(pv.y); pf.z = b2f(pv.z); pf.w = b2f(pv.w);
            float* ap = attn_out + ((size_t)bh * 2048 + q0 + wave * 16 + pr) * 2048 + s0 + pc;
            *(float4*)ap = pf;
        }
        // context MFMAs: P (A-layout from LDS) x V^T
        bf16x8 pa0 = *(const bf16x8*)&Psm[wave][l16][quad * 8];
        bf16x8 pa1 = *(const bf16x8*)&Psm[wave][l16][32 + quad * 8];
#pragma unroll
        for (int dt = 0; dt < 4; ++dt) {
            bf16x8 bv0 = *(const bf16x8*)&Vsm[dt * 16 + l16][quad * 8];
            bf16x8 bv1 = *(const bf16x8*)&Vsm[dt * 16 + l16][32 + quad * 8];
            cacc[dt] = __builtin_amdgcn_mfma_f32_16x16x32_bf16(pa0, bv0, cacc[dt], 0, 0, 0);
            cacc[dt] = __builtin_amdgcn_mfma_f32_16x16x32_bf16(pa1, bv1, cacc[dt], 0, 0, 0);
        }
        __syncthreads();
    }

    // context -> [b][s][h*64+d] bf16
#pragma unroll
    for (int dt = 0; dt < 4; ++dt) {
        const int d = dt * 16 + l16;
#pragma unroll
        for (int r = 0; r < 4; ++r) {
            const int s = q0 + wave * 16 + quad * 4 + r;
            ctx_ws[((size_t)b * 2048 + s) * 1024 + h * 64 + d] = f2b(cacc[dt][r]);
        }
    }
}

// ---------- output projection + bias + residual -> fp32 (m97 structure, 128x128 tile) ----------
__global__ __launch_bounds__(256) void out_proj_k(const u16* __restrict__ Ctx, const u16* __restrict__ WtO,
                                                  const float* __restrict__ bo, const float* __restrict__ Qin,
                                                  float* __restrict__ ln_in) {
    __shared__ u16 Asm[128 * 32];
    __shared__ u16 Bsm[128 * 32];
    const int tid = threadIdx.x;
    const int wave = tid >> 6, lane = tid & 63, quad = lane >> 4, l16 = lane & 15;
    const int wr = wave >> 1, wc = wave & 1;
    const int m0 = blockIdx.y * 128, n0 = blockIdx.x * 128;

    const u16* Ag = Ctx + (size_t)(m0 + (tid >> 2)) * 1024 + (tid & 3) * 8;
    const u16* Bg = WtO + (size_t)(n0 + (tid >> 2)) * 1024 + (tid & 3) * 8;

    const f32x4 zero = {0.f, 0.f, 0.f, 0.f};
    f32x4 acc[4][4];
#pragma unroll
    for (int i = 0; i < 4; ++i)
#pragma unroll
        for (int j = 0; j < 4; ++j) acc[i][j] = zero;

    for (int k0 = 0; k0 < 1024; k0 += 32) {
        GLOAD16(Ag + k0, &Asm[tid * 8]);
        GLOAD16(Ag + k0 + (size_t)64 * 1024, &Asm[2048 + tid * 8]);
        GLOAD16(Bg + k0, &Bsm[tid * 8]);
        GLOAD16(Bg + k0 + (size_t)64 * 1024, &Bsm[2048 + tid * 8]);
        __syncthreads();
        bf16x8 a[4], b[4];
#pragma unroll
        for (int i = 0; i < 4; ++i) {
            a[i] = *(const bf16x8*)&Asm[(wr * 64 + i * 16 + l16) * 32 + quad * 8];
            b[i] = *(const bf16x8*)&Bsm[(wc * 64 + i * 16 + l16) * 32 + quad * 8];
        }
#pragma unroll
        for (int mi = 0; mi < 4; ++mi)
#pragma unroll
            for (int ni = 0; ni < 4; ++ni)
                acc[mi][ni] = __builtin_amdgcn_mfma_f32_16x16x32_bf16(a[mi], b[ni], acc[mi][ni], 0, 0, 0);
        __syncthreads();
    }
#pragma unroll
    for (int ni = 0; ni < 4; ++ni) {
        const int n = n0 + wc * 64 + ni * 16 + l16;
        const float bsf = bo[n];
#pragma unroll
        for (int mi = 0; mi < 4; ++mi)
#pragma unroll
            for (int r = 0; r < 4; ++r) {
                const int m = m0 + wr * 64 + mi * 16 + quad * 4 + r;
                ln_in[(size_t)m * 1024 + n] = acc[mi][ni][r] + bsf + Qin[(size_t)m * 1024 + n];
            }
    }
}

// ---------- LayerNorm over D=1024, fp32 in -> fp32 out ----------
__global__ __launch_bounds__(256) void layernorm_k(const float* __restrict__ x, const float* __restrict__ g,
                                                   const float* __restrict__ bta, float* __restrict__ out) {
    const int row = blockIdx.x, tid = threadIdx.x;
    const float4 v = *(const float4*)(x + (size_t)row * 1024 + tid * 4);
    float s = v.x + v.y + v.z + v.w;
    float sq = v.x * v.x + v.y * v.y + v.z * v.z + v.w * v.w;
#pragma unroll
    for (int off = 32; off; off >>= 1) {
        s += __shfl_xor(s, off, 64);
        sq += __shfl_xor(sq, off, 64);
    }
    __shared__ float ss[4], ssq[4];
    const int wave = tid >> 6, lane = tid & 63;
    if (lane == 0) { ss[wave] = s; ssq[wave] = sq; }
    __syncthreads();
    const float S = ss[0] + ss[1] + ss[2] + ss[3];
    const float SQ = ssq[0] + ssq[1] + ssq[2] + ssq[3];
    const float mu = S * (1.f / 1024.f);
    const float rs = rsqrtf(SQ * (1.f / 1024.f) - mu * mu + 1e-5f);
    const float* vf = (const float*)&v;
    float4 o;
    float tmp[4];
#pragma unroll
    for (int j = 0; j < 4; ++j) {
        const int c = tid * 4 + j;
        tmp[j] = (vf[j] - mu) * rs * g[c] + bta[c];
    }
    o.x = tmp[0]; o.y = tmp[1]; o.z = tmp[2]; o.w = tmp[3];
    *(float4*)(out + (size_t)row * 1024 + tid * 4) = o;
}

extern "C" void kernel_launch(void* const* d_in, const int* in_sizes, int n_in,
                              void* d_out, int out_size, void* d_ws, size_t ws_size,
                              hipStream_t stream) {
    const float* Q  = (const float*)d_in[0];
    // d_in[1] (K) and d_in[2] (V) are unused: reference computes k,v from Q.
    const int* mask = (const int*)d_in[3];
    const float* Wq = (const float*)d_in[4];
    const float* bq = (const float*)d_in[5];
    const float* Wk = (const float*)d_in[6];
    const float* bk = (const float*)d_in[7];
    const float* Wv = (const float*)d_in[8];
    const float* bv = (const float*)d_in[9];
    const float* Wo = (const float*)d_in[10];
    const float* bo = (const float*)d_in[11];
    const float* g  = (const float*)d_in[12];
    const float* be = (const float*)d_in[13];

    char* ws = (char*)d_ws;
    u16* WtAll = (u16*)(ws);                          //  8 MB: Wq^T,Wk^T,Wv^T,Wo^T (bf16, [n][k])
    u16* q_ws  = (u16*)(ws + ((size_t)8  << 20));     //  8 MB [b,h,s,d] bf16 (q pre-scaled)
    u16* k_ws  = (u16*)(ws + ((size_t)16 << 20));     //  8 MB
    u16* v_ws  = (u16*)(ws + ((size_t)24 << 20));     //  8 MB
    u16* c_ws  = (u16*)(ws + ((size_t)32 << 20));     //  8 MB [b,s,h*64+d] bf16
    // 40..48 MB is time-shared: qbf (dead after gemm_qkv) -> vT (dead after attn) -> ln_in[0:8MB]
    u16* qbf   = (u16*)(ws + ((size_t)40 << 20));     //  8 MB Q bf16 [4096][1024]
    u16* vT    = (u16*)(ws + ((size_t)40 << 20));     //  8 MB [bh][d][s] bf16
    float* ln_in = (float*)(ws + ((size_t)40 << 20)); // 16 MB fp32 (40..56)
    unsigned long long* mbits = (unsigned long long*)(ws + ((size_t)56 << 20)); // 1 MB

    float* out_ln = (float*)d_out;
    float* out_at = (float*)d_out + (size_t)2 * 2048 * 1024;

    transpose_w_k<<<dim3(32, 32, 4), dim3(256), 0, stream>>>(Wq, Wk, Wv, Wo, WtAll);
    pack_mask_k<<<dim3(4096), dim3(256), 0, stream>>>(mask, mbits);
    qcvt_k<<<dim3(2048), dim3(256), 0, stream>>>(Q, qbf);
    gemm_qkv_k<<<dim3(24, 32), dim3(256), 0, stream>>>(qbf, WtAll, bq, bk, bv, q_ws, k_ws, v_ws);
    vtr_k<<<dim3(64, 2, 32), dim3(256), 0, stream>>>(v_ws, vT);
    attn_k<<<dim3(32, 32), dim3(256), 0, stream>>>(q_ws, k_ws, vT, mbits, out_at, c_ws);
    out_proj_k<<<dim3(8, 32), dim3(256), 0, stream>>>(c_ws, WtAll + (size_t)3 * 1024 * 1024, bo, Q, ln_in);
    layernorm_k<<<dim3(4096), dim3(256), 0, stream>>>(ln_in, g, be, out_ln);
    (void)in_sizes; (void)n_in; (void)out_size; (void)ws_size;
}